// Round 10
// baseline (13611.176 us; speedup 1.0000x reference)
//
#include <hip/hip_runtime.h>
#include <hip/hip_bf16.h>
#include <cstdint>
#include <cstddef>

// Problem: S=4096, I=1024, H=1024. 4H=4096. ALL tensors fp32 (per reference).
// out (fp32): all_hidden (4096 x 2048) then final_h (2048), flat.

typedef __attribute__((ext_vector_type(8))) short short8;
typedef __attribute__((ext_vector_type(4))) short short4v;
typedef __attribute__((ext_vector_type(4))) float float4v;
typedef __attribute__((ext_vector_type(2))) float float2v;
typedef unsigned long long ull;

__device__ __forceinline__ float bf2f(unsigned short u) {
    return __uint_as_float(((unsigned int)u) << 16);
}
__device__ __forceinline__ unsigned short f2bf(float f) {
    __hip_bfloat16 h = __float2bfloat16(f);  // RNE
    return *reinterpret_cast<unsigned short*>(&h);
}
__device__ __forceinline__ float sigm(float x) {
    return 1.f / (1.f + __expf(-x));
}
__device__ __forceinline__ float tanh_fast(float x) {
    return 1.f - 2.f / (__expf(2.f * x) + 1.f);   // exact at +-inf, ~1e-6 rel
}

// ---------------------------------------------------------------------------
// Kernel A: x_proj[d][t][j] = b[d][j] + sum_k inp[t][k] * W[d][j][1024+k]
// fp32 -> bf16 LDS tiles -> mfma_f32_16x16x32_bf16 -> fp32 x_proj.
// ---------------------------------------------------------------------------
__global__ __launch_bounds__(256)
void xproj_gemm(const float* __restrict__ inp,
                const float* __restrict__ fw,
                const float* __restrict__ fb,
                const float* __restrict__ bw,
                const float* __restrict__ bb,
                float* __restrict__ xp)
{
    const int d  = blockIdx.z;
    const float* W = d ? bw : fw;
    const float* B = d ? bb : fb;
    const int t0 = blockIdx.y * 128;
    const int n0 = blockIdx.x * 128;

    __shared__ __align__(16) short Ash[128 * 32];
    __shared__ __align__(16) short Bsh[128 * 32];

    const int tid  = threadIdx.x;
    const int lane = tid & 63;
    const int wave = tid >> 6;
    const int wm = (wave & 1) * 64;
    const int wn = (wave >> 1) * 64;
    const int quad = lane >> 4;
    const int l15  = lane & 15;

    float4v acc[4][4];
    float4v zero4 = {0.f, 0.f, 0.f, 0.f};
#pragma unroll
    for (int mi = 0; mi < 4; mi++)
#pragma unroll
        for (int ni = 0; ni < 4; ni++) acc[mi][ni] = zero4;

    for (int k0 = 0; k0 < 1024; k0 += 32) {
#pragma unroll
        for (int s = 0; s < 4; s++) {
            int c   = tid + s * 256;       // 0..1023
            int row = c >> 3;              // 0..127
            int ko  = (c & 7) * 4;         // 0..28
            float4v va = *(const float4v*)&inp[(size_t)(t0 + row) * 1024 + k0 + ko];
            float4v vb = *(const float4v*)&W[(size_t)(n0 + row) * 2048 + 1024 + k0 + ko];
            short4v sa, sb;
#pragma unroll
            for (int e = 0; e < 4; e++) {
                sa[e] = (short)f2bf(va[e]);
                sb[e] = (short)f2bf(vb[e]);
            }
            *(short4v*)&Ash[row * 32 + ko] = sa;
            *(short4v*)&Bsh[row * 32 + ko] = sb;
        }
        __syncthreads();

        short8 af[4], bfr[4];
#pragma unroll
        for (int mi = 0; mi < 4; mi++)
            af[mi] = *(const short8*)&Ash[(wm + mi * 16 + l15) * 32 + quad * 8];
#pragma unroll
        for (int ni = 0; ni < 4; ni++)
            bfr[ni] = *(const short8*)&Bsh[(wn + ni * 16 + l15) * 32 + quad * 8];

#pragma unroll
        for (int mi = 0; mi < 4; mi++)
#pragma unroll
            for (int ni = 0; ni < 4; ni++)
                acc[mi][ni] = __builtin_amdgcn_mfma_f32_16x16x32_bf16(
                    af[mi], bfr[ni], acc[mi][ni], 0, 0, 0);
        __syncthreads();
    }

#pragma unroll
    for (int ni = 0; ni < 4; ni++) {
        int gc = n0 + wn + ni * 16 + l15;
        float bias = B[gc];
#pragma unroll
        for (int mi = 0; mi < 4; mi++) {
#pragma unroll
            for (int r = 0; r < 4; r++) {
                int gr = t0 + wm + mi * 16 + quad * 4 + r;
                xp[((size_t)d * 4096 + gr) * 4096 + gc] = acc[mi][ni][r] + bias;
            }
        }
    }
}

// ---------------------------------------------------------------------------
// Kernel B: persistent bidirectional LSTM recurrence, fence-free tagged sync.
//
// Sync scheme (r4-proven): hq is uint32[dir][2][1024]; each word = fp32 h
// with its 2 LOW MANTISSA BITS replaced by (step & 3). Parity double-buffer:
// a polled slot only ever holds step t or t-2 -> 2-bit tag disambiguates;
// perturbation <=3 ulp. memset-0 init == tag 0 == h^0. Poll: ONE 8B relaxed
// agent-scope atomic load covers 2 adjacent units; merged check + s_sleep(1)
// backoff (r3-proven optimum; r7 deeper spin and r8 wave-autonomous poll
// both regressed). Publish: per-wave 8B atomic store.
//
// Structure: 128 blocks x 512 threads, 16 units/block. NO pre-FMA barrier:
// wave w's hsh segment [128w,+128) is written/read only by itself
// (lgkmcnt(0) orders it); each wave enters FMA on its OWN detect; coupling
// deferred to S2 where FMA time absorbs straggler spread.
// GEMV inner loop: v_pk_fma_f32 via <2 x float> fma (r9: -11%, VALUBusy
// 14.2->8.9%).
//
// Round-10 change: post-S2 PER-WAVE PARALLEL epilogue. Previously wave 0
// alone reduced all 64 rows (8 serial-ish LDS reads/row batch + shfl +
// gates + 16x4B publish) while 7 waves idled (~400-600 cy). Now wave w
// finishes its own units {u0+2w,+1}: lane l reads ONE psum (row l>>3,
// chunk l&7), shfl_xor 1/2/4 reduces each 8-lane group, 4 shfls gather
// the gates, all lanes compute gates for parity l&1 (replicated, free),
// lane 0 publishes the wave's 8B pair + float2 out store. The 8 wave
// epilogues and publishes run in parallel. xp/bias base value moves to
// the (l&7)==0 lane of each row group (loaded pre-poll).
//
// Safety (unchanged): publish(t+1) follows S2(t), which requires ALL the
// block's tag-t polls (each block polls all 1024 words); overwriting
// step t-1 slots at publish(t+1) transitively requires every block
// consumed t-1. psum is parity-double-buffered; earliest rewrite of
// psum[par] is at t+2, after S2(t+1), which follows every wave's
// epilogue(t) in program order.
// ---------------------------------------------------------------------------
template <int FUSED>
__global__ __launch_bounds__(512, 1)
void lstm_rec(const float* __restrict__ fw,
              const float* __restrict__ bw,
              const float* __restrict__ fb,
              const float* __restrict__ bb,
              const float* __restrict__ inp,
              const float* __restrict__ xp,
              unsigned int* __restrict__ hq,     // [dir][2][1024] tagged f32
              float* __restrict__ out)
{
    const int dir  = blockIdx.x & 1;
    const int slot = blockIdx.x >> 1;          // 0..63
    const int u0   = slot * 16;                // 16 units per block
    const int T    = threadIdx.x;              // 0..511
    const int rl   = T & 63;                   // z-row-local 0..63
    const int gate = rl >> 4;
    const int ul   = rl & 15;
    const int chunk = T >> 6;                  // wave id 0..7 (128-col chunk)
    const int wv   = chunk;
    const int l    = T & 63;                   // lane
    const int j    = gate * 1024 + u0 + ul;    // this thread's GEMV z-row
    const float* W = dir ? bw : fw;

    // epilogue mapping: wave wv owns units {u0+2wv, u0+2wv+1}
    const int er   = l >> 3;                   // local row 0..7 (= gate*2+p)
    const int eg   = er >> 1;                  // gate of local row
    const int ep   = er & 1;                   // unit parity of local row
    const int ug   = u0 + 2 * wv;              // wave's even unit
    const int jrow = eg * 1024 + ug + ep;      // global z-row of local row er
    const int prow = eg * 16 + 2 * wv + ep;    // psum row of local row er
    const int pp   = l & 1;                    // gate-compute parity

    __shared__ __align__(16) float hsh[1024];
    __shared__ __align__(16) float xsh[1024];     // FUSED only
    __shared__ float psum[2][64 * 9];             // per-parity partials

    // Wh weights (cols [chunk*128,+128) of row j) -> float2v register pairs
    float2v wA[32], wB[32];
    {
        const float* wr = W + (size_t)j * 2048 + chunk * 128;
#pragma unroll
        for (int i = 0; i < 32; i++) {
            float4v v = *(const float4v*)&wr[4 * i];
            wA[i] = (float2v){v.x, v.y};
            wB[i] = (float2v){v.z, v.w};
        }
    }

    // FUSED: Wx packed bf16 + per-row-group bias
    unsigned int w2[64];
    float brow = 0.f;
    if (FUSED) {
        const float* wr2 = W + (size_t)j * 2048 + 1024 + chunk * 128;
#pragma unroll
        for (int i = 0; i < 32; i++) {
            float4v v = *(const float4v*)&wr2[4 * i];
            w2[2 * i]     = (unsigned int)f2bf(v[0]) | ((unsigned int)f2bf(v[1]) << 16);
            w2[2 * i + 1] = (unsigned int)f2bf(v[2]) | ((unsigned int)f2bf(v[3]) << 16);
        }
        if ((l & 7) == 0)
            brow = (dir ? bb : fb)[jrow];
    }

    unsigned int* hqd = hq + dir * 2048;
    float c = 0.f;   // cell state for unit ug+pp (replicated per parity)

    for (int t = 0; t < 4096; t++) {
        const int tr  = dir ? (4095 - t) : t;
        const int par = t & 1;

        // independent global loads first (long latency, off critical path)
        float xv = 0.f;
        float2 iv;
        if (FUSED) {
            iv = ((const float2*)&inp[(size_t)tr * 1024])[T];
        } else if ((l & 7) == 0) {
            xv = xp[((size_t)dir * 4096 + tr) * 4096 + jrow];
        }

        // poll pair T (units 2T,2T+1) with ONE 8B load; 2-bit embedded tags
        {
            const ull tag2 = ((ull)((unsigned)t & 3u)) * 0x100000001ull;
            ull* q0 = (ull*)(hqd + par * 1024 + 2 * T);
            ull w0 = __hip_atomic_load(q0, __ATOMIC_RELAXED, __HIP_MEMORY_SCOPE_AGENT);
            while ((w0 & 0x0000000300000003ull) != tag2) {
                __builtin_amdgcn_s_sleep(1);   // ~64 cy backoff, decongest fabric
                w0 = __hip_atomic_load(q0, __ATOMIC_RELAXED, __HIP_MEMORY_SCOPE_AGENT);
            }
            *(ull*)&hsh[2 * T] = w0;   // raw bits; tag bits are <=3 ulp noise
        }
        if (FUSED) {
            xsh[2 * T]     = iv.x;
            xsh[2 * T + 1] = iv.y;
        }
        // NO block barrier: hsh/xsh segment [chunk*128,+128) is private to
        // this wave. Order the same-wave LDS write->read explicitly.
        asm volatile("s_waitcnt lgkmcnt(0)" ::: "memory");

        // z partial: 64 packed-fp32 FMAs (v_pk_fma_f32; wave-broadcast LDS)
        float2v ac01 = {0.f, 0.f}, ac23 = {0.f, 0.f};
        const float4v* h4 = (const float4v*)&hsh[chunk * 128];
#pragma unroll
        for (int i = 0; i < 32; i++) {
            float4v hv = h4[i];
            float2v h01 = {hv.x, hv.y};
            float2v h23 = {hv.z, hv.w};
            ac01 = __builtin_elementwise_fma(wA[i], h01, ac01);
            ac23 = __builtin_elementwise_fma(wB[i], h23, ac23);
        }
        if (FUSED) {
            const float* xs = &xsh[chunk * 128];
#pragma unroll
            for (int i = 0; i < 64; i++) {
                unsigned int dv = w2[i];
                float2v xp2 = {xs[2 * i], xs[2 * i + 1]};
                float2v wd = {bf2f((unsigned short)(dv & 0xffffu)),
                              bf2f((unsigned short)(dv >> 16))};
                ac01 = __builtin_elementwise_fma(wd, xp2, ac01);
            }
        }
        psum[par][rl * 9 + chunk] = (ac01[0] + ac01[1]) + (ac23[0] + ac23[1]);
        __syncthreads();   // S2: psum ready

        // per-wave parallel epilogue: wave wv finishes units {ug, ug+1}.
        // lane l: row er=l>>3, chunk l&7 -> one psum read; shfl_xor tree
        // over the 8-lane group; shfl-gather gates; publish 8B pair.
        {
            float s = psum[par][prow * 9 + (l & 7)];
            if ((l & 7) == 0) s += (FUSED ? brow : xv);
            s += __shfl_xor(s, 1);
            s += __shfl_xor(s, 2);
            s += __shfl_xor(s, 4);
            // every lane of group er holds full z for row er
            float z0 = __shfl(s, 8 * (0 + pp));     // gate f (er = 0+pp)
            float z1 = __shfl(s, 8 * (2 + pp));     // gate i (er = 2+pp)
            float z2 = __shfl(s, 8 * (4 + pp));     // gate g (er = 4+pp)
            float z3 = __shfl(s, 8 * (6 + pp));     // gate o (er = 6+pp)
            c = sigm(z0) * c + sigm(z1) * tanh_fast(z2);
            float hv = sigm(z3) * tanh_fast(c);
            // publish FIRST (critical path), then out stores
            unsigned int hb = (__float_as_uint(hv) & ~3u)
                            | ((unsigned)(t + 1) & 3u);
            unsigned int hb1 = __shfl(hb, 1);
            float hv1 = __shfl(hv, 1);
            if (l == 0) {
                ull pw = ((ull)hb1 << 32) | (ull)hb;
                __hip_atomic_store((ull*)&hqd[((t + 1) & 1) * 1024 + ug], pw,
                                   __ATOMIC_RELAXED, __HIP_MEMORY_SCOPE_AGENT);
                float2 o2 = {hv, hv1};
                *(float2*)&out[(size_t)tr * 2048 + dir * 1024 + ug] = o2;
                if (t == 4095)   // final_h: fwd = hs[4095], bwd = hs[0]
                    *(float2*)&out[(size_t)4096 * 2048 + dir * 1024 + ug] = o2;
            }
        }
    }
}

// ---------------------------------------------------------------------------
extern "C" void kernel_launch(void* const* d_in, const int* in_sizes, int n_in,
                              void* d_out, int out_size, void* d_ws, size_t ws_size,
                              hipStream_t stream)
{
    const float* inp = (const float*)d_in[0];
    const float* fw  = (const float*)d_in[1];
    const float* fb  = (const float*)d_in[2];
    const float* bw  = (const float*)d_in[3];
    const float* bb  = (const float*)d_in[4];

    char* ws = (char*)d_ws;
    unsigned int* hq = (unsigned int*)ws;          // 16 KB: [dir][2][1024] x 4B
    float* xp = (float*)(ws + 32768);              // x_proj: 2 x 4096 x 4096 fp32

    const size_t XP_BYTES = 2ull * 4096 * 4096 * 4;   // 134.2 MB
    const int have_xp = (ws_size >= 32768 + XP_BYTES);

    hipMemsetAsync(ws, 0, 16384, stream);   // tag 0 / h=0 == step-0 state

    float* outp = (float*)d_out;
    if (have_xp) {
        dim3 gg(32, 32, 2);
        xproj_gemm<<<gg, 256, 0, stream>>>(inp, fw, fb, bw, bb, xp);
        lstm_rec<0><<<dim3(128), 512, 0, stream>>>(fw, bw, fb, bb, inp, xp,
                                                   hq, outp);
    } else {
        lstm_rec<1><<<dim3(128), 512, 0, stream>>>(fw, bw, fb, bb, inp, nullptr,
                                                   hq, outp);
    }
}

// Round 11
// 8108.181 us; speedup vs baseline: 1.6787x; 1.6787x over previous
//
#include <hip/hip_runtime.h>
#include <hip/hip_bf16.h>
#include <cstdint>
#include <cstddef>

// Problem: S=4096, I=1024, H=1024. 4H=4096. ALL tensors fp32 (per reference).
// out (fp32): all_hidden (4096 x 2048) then final_h (2048), flat.

typedef __attribute__((ext_vector_type(8))) short short8;
typedef __attribute__((ext_vector_type(4))) short short4v;
typedef __attribute__((ext_vector_type(4))) float float4v;
typedef __attribute__((ext_vector_type(2))) float float2v;
typedef unsigned long long ull;

__device__ __forceinline__ float bf2f(unsigned short u) {
    return __uint_as_float(((unsigned int)u) << 16);
}
__device__ __forceinline__ unsigned short f2bf(float f) {
    __hip_bfloat16 h = __float2bfloat16(f);  // RNE
    return *reinterpret_cast<unsigned short*>(&h);
}
__device__ __forceinline__ float sigm(float x) {
    return 1.f / (1.f + __expf(-x));
}
__device__ __forceinline__ float tanh_fast(float x) {
    return 1.f - 2.f / (__expf(2.f * x) + 1.f);   // exact at +-inf, ~1e-6 rel
}

// ---------------------------------------------------------------------------
// Kernel A: x_proj[d][t][j] = b[d][j] + sum_k inp[t][k] * W[d][j][1024+k]
// fp32 -> bf16 LDS tiles -> mfma_f32_16x16x32_bf16 -> fp32 x_proj.
// ---------------------------------------------------------------------------
__global__ __launch_bounds__(256)
void xproj_gemm(const float* __restrict__ inp,
                const float* __restrict__ fw,
                const float* __restrict__ fb,
                const float* __restrict__ bw,
                const float* __restrict__ bb,
                float* __restrict__ xp)
{
    const int d  = blockIdx.z;
    const float* W = d ? bw : fw;
    const float* B = d ? bb : fb;
    const int t0 = blockIdx.y * 128;
    const int n0 = blockIdx.x * 128;

    __shared__ __align__(16) short Ash[128 * 32];
    __shared__ __align__(16) short Bsh[128 * 32];

    const int tid  = threadIdx.x;
    const int lane = tid & 63;
    const int wave = tid >> 6;
    const int wm = (wave & 1) * 64;
    const int wn = (wave >> 1) * 64;
    const int quad = lane >> 4;
    const int l15  = lane & 15;

    float4v acc[4][4];
    float4v zero4 = {0.f, 0.f, 0.f, 0.f};
#pragma unroll
    for (int mi = 0; mi < 4; mi++)
#pragma unroll
        for (int ni = 0; ni < 4; ni++) acc[mi][ni] = zero4;

    for (int k0 = 0; k0 < 1024; k0 += 32) {
#pragma unroll
        for (int s = 0; s < 4; s++) {
            int c   = tid + s * 256;       // 0..1023
            int row = c >> 3;              // 0..127
            int ko  = (c & 7) * 4;         // 0..28
            float4v va = *(const float4v*)&inp[(size_t)(t0 + row) * 1024 + k0 + ko];
            float4v vb = *(const float4v*)&W[(size_t)(n0 + row) * 2048 + 1024 + k0 + ko];
            short4v sa, sb;
#pragma unroll
            for (int e = 0; e < 4; e++) {
                sa[e] = (short)f2bf(va[e]);
                sb[e] = (short)f2bf(vb[e]);
            }
            *(short4v*)&Ash[row * 32 + ko] = sa;
            *(short4v*)&Bsh[row * 32 + ko] = sb;
        }
        __syncthreads();

        short8 af[4], bfr[4];
#pragma unroll
        for (int mi = 0; mi < 4; mi++)
            af[mi] = *(const short8*)&Ash[(wm + mi * 16 + l15) * 32 + quad * 8];
#pragma unroll
        for (int ni = 0; ni < 4; ni++)
            bfr[ni] = *(const short8*)&Bsh[(wn + ni * 16 + l15) * 32 + quad * 8];

#pragma unroll
        for (int mi = 0; mi < 4; mi++)
#pragma unroll
            for (int ni = 0; ni < 4; ni++)
                acc[mi][ni] = __builtin_amdgcn_mfma_f32_16x16x32_bf16(
                    af[mi], bfr[ni], acc[mi][ni], 0, 0, 0);
        __syncthreads();
    }

#pragma unroll
    for (int ni = 0; ni < 4; ni++) {
        int gc = n0 + wn + ni * 16 + l15;
        float bias = B[gc];
#pragma unroll
        for (int mi = 0; mi < 4; mi++) {
#pragma unroll
            for (int r = 0; r < 4; r++) {
                int gr = t0 + wm + mi * 16 + quad * 4 + r;
                xp[((size_t)d * 4096 + gr) * 4096 + gc] = acc[mi][ni][r] + bias;
            }
        }
    }
}

// ---------------------------------------------------------------------------
// Kernel B: persistent bidirectional LSTM recurrence, fence-free tagged sync.
//
// Sync scheme: hq is uint32[dir][2 parity][2 REPLICA][1024]; each word =
// fp32 h with its 2 LOW MANTISSA BITS replaced by (step & 3). Parity
// double-buffer: a polled slot only ever holds step t or t-2 -> 2-bit tag
// disambiguates; perturbation <=3 ulp. memset-0 init == tag 0 == h^0.
//
// Round-11 change (detect-period attack, r7-failure-informed): the spin's
// check period was pinned at ~RTT+sleep because ALL in-flight loads to the
// SAME address share one MSHR and return together (this is why r7's 4-deep
// same-address pipeline regressed). Producers now publish each tagged word
// to TWO REPLICAS on different 64B lines (4 KB apart); consumers run an
// alternating two-stream spin (check A -> reload A -> check B -> reload B,
// no sleep). Distinct lines -> distinct MSHRs -> interleaved returns ->
// check period ~RTT/2, and the s_sleep's +64cy is gone. <=2 outstanding
// loads/thread (r8's 8-deep congestion collapse stays far away). Publishes
// remain line-coalesced single-wave stores (r10's scattered per-wave 8B
// same-line stores serialized at the LLC: WRITE 65->164MB, -90% perf).
//
// Structure (r9-proven, 7613 us): 128 blocks x 512 threads, 16 units/block.
// NO pre-FMA barrier: wave w's hsh segment [128w,+128) is written/read only
// by itself (lgkmcnt(0) orders it); each wave enters FMA on its OWN detect;
// coupling deferred to S2. GEMV inner loop: v_pk_fma_f32 via <2 x float>
// fma (r9: -11%). Serial wave-0 epilogue (parallel variant regressed, r10).
//
// Safety: publish(t+1) follows S2(t), which requires all the block's tag-t
// polls; a successful poll needs only ONE replica, but a publish covers
// BOTH, so the induction (publish(t+1) => every block consumed t-1 =>
// overwriting t-1's replicas is safe) holds unchanged.
// ---------------------------------------------------------------------------
template <int FUSED>
__global__ __launch_bounds__(512, 1)
void lstm_rec(const float* __restrict__ fw,
              const float* __restrict__ bw,
              const float* __restrict__ fb,
              const float* __restrict__ bb,
              const float* __restrict__ inp,
              const float* __restrict__ xp,
              unsigned int* __restrict__ hq,     // [dir][2][2][1024] tagged f32
              float* __restrict__ out)
{
    const int dir  = blockIdx.x & 1;
    const int slot = blockIdx.x >> 1;          // 0..63
    const int u0   = slot * 16;                // 16 units per block
    const int T    = threadIdx.x;              // 0..511
    const int rl   = T & 63;                   // z-row-local 0..63
    const int gate = rl >> 4;
    const int ul   = rl & 15;
    const int chunk = T >> 6;                  // wave id 0..7 (128-col chunk)
    const int j    = gate * 1024 + u0 + ul;    // global z-row
    const float* W = dir ? bw : fw;

    __shared__ __align__(16) float hsh[1024];
    __shared__ __align__(16) float xsh[1024];     // FUSED only
    __shared__ float psum[2][64 * 9];             // per-parity partials

    // Wh weights (cols [chunk*128,+128) of row j) -> float2v register pairs
    float2v wA[32], wB[32];
    {
        const float* wr = W + (size_t)j * 2048 + chunk * 128;
#pragma unroll
        for (int i = 0; i < 32; i++) {
            float4v v = *(const float4v*)&wr[4 * i];
            wA[i] = (float2v){v.x, v.y};
            wB[i] = (float2v){v.z, v.w};
        }
    }

    // FUSED: Wx packed bf16 + per-row bias
    unsigned int w2[64];
    float brow = 0.f;
    if (FUSED) {
        const float* wr2 = W + (size_t)j * 2048 + 1024 + chunk * 128;
#pragma unroll
        for (int i = 0; i < 32; i++) {
            float4v v = *(const float4v*)&wr2[4 * i];
            w2[2 * i]     = (unsigned int)f2bf(v[0]) | ((unsigned int)f2bf(v[1]) << 16);
            w2[2 * i + 1] = (unsigned int)f2bf(v[2]) | ((unsigned int)f2bf(v[3]) << 16);
        }
        if (T < 64)
            brow = (dir ? bb : fb)[(T >> 4) * 1024 + u0 + (T & 15)];
    }

    unsigned int* hqd = hq + dir * 4096;       // [par][rep][1024]
    float c = 0.f;   // cell state for unit u0+T (threads T<16)

    for (int t = 0; t < 4096; t++) {
        const int tr  = dir ? (4095 - t) : t;
        const int par = t & 1;

        // independent global loads first (long latency, off critical path)
        float xv = 0.f;
        float2 iv;
        if (FUSED) {
            iv = ((const float2*)&inp[(size_t)tr * 1024])[T];
        } else if (T < 64) {
            xv = xp[((size_t)dir * 4096 + tr) * 4096 + j];
        }

        // poll pair T (units 2T,2T+1): alternating TWO-REPLICA spin.
        // Replicas live on different 64B lines -> separate MSHRs -> the two
        // outstanding loads return interleaved -> check period ~RTT/2.
        {
            const ull tagm = 0x0000000300000003ull;
            const ull tag2 = ((ull)((unsigned)t & 3u)) * 0x100000001ull;
            ull* qA = (ull*)(hqd + par * 2048 + 2 * T);
            ull* qB = (ull*)(hqd + par * 2048 + 1024 + 2 * T);
            ull a = __hip_atomic_load(qA, __ATOMIC_RELAXED, __HIP_MEMORY_SCOPE_AGENT);
            ull b = __hip_atomic_load(qB, __ATOMIC_RELAXED, __HIP_MEMORY_SCOPE_AGENT);
            ull got;
            for (;;) {
                if ((a & tagm) == tag2) { got = a; break; }
                a = __hip_atomic_load(qA, __ATOMIC_RELAXED, __HIP_MEMORY_SCOPE_AGENT);
                if ((b & tagm) == tag2) { got = b; break; }
                b = __hip_atomic_load(qB, __ATOMIC_RELAXED, __HIP_MEMORY_SCOPE_AGENT);
            }
            *(ull*)&hsh[2 * T] = got;   // raw bits; tag bits are <=3 ulp noise
        }
        if (FUSED) {
            xsh[2 * T]     = iv.x;
            xsh[2 * T + 1] = iv.y;
        }
        // NO block barrier: hsh/xsh segment [chunk*128,+128) is private to
        // this wave. Order the same-wave LDS write->read explicitly.
        asm volatile("s_waitcnt lgkmcnt(0)" ::: "memory");

        // z partial: 64 packed-fp32 FMAs (v_pk_fma_f32; wave-broadcast LDS)
        float2v ac01 = {0.f, 0.f}, ac23 = {0.f, 0.f};
        const float4v* h4 = (const float4v*)&hsh[chunk * 128];
#pragma unroll
        for (int i = 0; i < 32; i++) {
            float4v hv = h4[i];
            float2v h01 = {hv.x, hv.y};
            float2v h23 = {hv.z, hv.w};
            ac01 = __builtin_elementwise_fma(wA[i], h01, ac01);
            ac23 = __builtin_elementwise_fma(wB[i], h23, ac23);
        }
        if (FUSED) {
            const float* xs = &xsh[chunk * 128];
#pragma unroll
            for (int i = 0; i < 64; i++) {
                unsigned int dv = w2[i];
                float2v xp2 = {xs[2 * i], xs[2 * i + 1]};
                float2v wd = {bf2f((unsigned short)(dv & 0xffffu)),
                              bf2f((unsigned short)(dv >> 16))};
                ac01 = __builtin_elementwise_fma(wd, xp2, ac01);
            }
        }
        psum[par][rl * 9 + chunk] = (ac01[0] + ac01[1]) + (ac23[0] + ac23[1]);
        __syncthreads();   // S2: psum ready

        // epilogue on wave 0: 64 row-reducers -> shfl gather -> 16 gate lanes.
        // Publish FIRST (critical path; both replicas, line-coalesced), then
        // the out stores.
        if (T < 64) {
            float s = FUSED ? brow : xv;
            const float* pp = &psum[par][T * 9];
#pragma unroll
            for (int cc = 0; cc < 8; cc++) s += pp[cc];
            const int u = T & 15;
            float z0 = __shfl(s, u);           // gate f: row u
            float z1 = __shfl(s, u + 16);      // gate i
            float z2 = __shfl(s, u + 32);      // gate g
            float z3 = __shfl(s, u + 48);      // gate o
            if (T < 16) {
                c = sigm(z0) * c + sigm(z1) * tanh_fast(z2);
                float hv = sigm(z3) * tanh_fast(c);
                unsigned int hb = (__float_as_uint(hv) & ~3u)
                                | ((unsigned)(t + 1) & 3u);
                unsigned int* pb = hqd + ((t + 1) & 1) * 2048;
                __hip_atomic_store(pb + u0 + T, hb,
                                   __ATOMIC_RELAXED, __HIP_MEMORY_SCOPE_AGENT);
                __hip_atomic_store(pb + 1024 + u0 + T, hb,
                                   __ATOMIC_RELAXED, __HIP_MEMORY_SCOPE_AGENT);
                out[(size_t)tr * 2048 + dir * 1024 + u0 + T] = hv;
                if (t == 4095)   // final_h: fwd = hs[4095], bwd = hs[0]
                    out[(size_t)4096 * 2048 + dir * 1024 + u0 + T] = hv;
            }
        }
    }
}

// ---------------------------------------------------------------------------
extern "C" void kernel_launch(void* const* d_in, const int* in_sizes, int n_in,
                              void* d_out, int out_size, void* d_ws, size_t ws_size,
                              hipStream_t stream)
{
    const float* inp = (const float*)d_in[0];
    const float* fw  = (const float*)d_in[1];
    const float* fb  = (const float*)d_in[2];
    const float* bw  = (const float*)d_in[3];
    const float* bb  = (const float*)d_in[4];

    char* ws = (char*)d_ws;
    unsigned int* hq = (unsigned int*)ws;          // 32 KB: [dir][2][2][1024] x 4B
    float* xp = (float*)(ws + 32768);              // x_proj: 2 x 4096 x 4096 fp32

    const size_t XP_BYTES = 2ull * 4096 * 4096 * 4;   // 134.2 MB
    const int have_xp = (ws_size >= 32768 + XP_BYTES);

    hipMemsetAsync(ws, 0, 32768, stream);   // tag 0 / h=0 == step-0 state

    float* outp = (float*)d_out;
    if (have_xp) {
        dim3 gg(32, 32, 2);
        xproj_gemm<<<gg, 256, 0, stream>>>(inp, fw, fb, bw, bb, xp);
        lstm_rec<0><<<dim3(128), 512, 0, stream>>>(fw, bw, fb, bb, inp, xp,
                                                   hq, outp);
    } else {
        lstm_rec<1><<<dim3(128), 512, 0, stream>>>(fw, bw, fb, bb, inp, nullptr,
                                                   hq, outp);
    }
}